// Round 1
// baseline (928.857 us; speedup 1.0000x reference)
//
#include <hip/hip_runtime.h>
#include <math.h>

#define NROWS 4096
#define D 128
#define SPC 8
#define KRET 7
#define MARGIN 0.2f

// ws layout (floats): [0] = loss_sum accum, [1] = count accum, [2 .. 2+NROWS) = diag
// diag[j] = dot(embeddings[j], embeddings1[j])  (diagonal of emb @ emb1.T)

__global__ __launch_bounds__(256) void diag_kernel(const float* __restrict__ emb,
                                                   const float* __restrict__ emb1,
                                                   float* __restrict__ diag) {
    int wave = threadIdx.x >> 6;
    int lane = threadIdx.x & 63;
    int row = blockIdx.x * 4 + wave;
    const float* a = emb + (size_t)row * D;
    const float* b = emb1 + (size_t)row * D;
    float s = a[lane] * b[lane] + a[lane + 64] * b[lane + 64];
    for (int off = 32; off > 0; off >>= 1) s += __shfl_down(s, off, 64);
    if (lane == 0) diag[row] = s;
}

__global__ __launch_bounds__(256) void main_kernel(const float* __restrict__ emb,
                                                   const float* __restrict__ emb1,
                                                   const int* __restrict__ labels,   // product_labels (columns)
                                                   const int* __restrict__ labels1,  // prod_labels1 (rows)
                                                   const float* __restrict__ diag,
                                                   float* __restrict__ ws_acc) {
    const int i = blockIdx.x;
    const int tid = threadIdx.x;

    __shared__ float s_anchor[D];             // embeddings[i]
    __shared__ float s_posd[SPC];             // cross-distance to each member of i's 8-group (slot j&7)
    __shared__ unsigned long long s_red[4];
    __shared__ unsigned long long s_win;
    __shared__ int s_negidx[KRET];
    __shared__ float s_negd[KRET];
    __shared__ float s_dreal[2 * KRET];       // [0..6] d_ap, [7..13] d_an

    if (tid < D) s_anchor[tid] = emb[(size_t)i * D + tid];
    __syncthreads();

    const float diag_i = diag[i];
    const int li = labels1[i];

    // ---- Phase 1: cross-distances for all 4096 j, 16 per thread ----
    float score[16];
#pragma unroll
    for (int it = 0; it < 16; ++it) {
        int j = it * 256 + tid;
        const float4* r = (const float4*)(emb1 + (size_t)j * D);
        float acc = 0.f;
#pragma unroll
        for (int q = 0; q < D / 4; ++q) {
            float4 v = r[q];
            acc = fmaf(v.x, s_anchor[4 * q + 0], acc);
            acc = fmaf(v.y, s_anchor[4 * q + 1], acc);
            acc = fmaf(v.z, s_anchor[4 * q + 2], acc);
            acc = fmaf(v.w, s_anchor[4 * q + 3], acc);
        }
        float d2 = diag_i + diag[j] - 2.f * acc;
        float dist = sqrtf(fmaxf(d2, 1e-4f));   // fuses max(d2,0) and max(d2,1e-4)
        bool is_pos = (labels[j] == li) && (j != i);
        if (is_pos) s_posd[j & (SPC - 1)] = dist;
        score[it] = dist + (is_pos ? 1e6f : 0.f);
    }
    __syncthreads();

    // ---- Phase 2: 7 rounds of block-wide argmin (tie-break: lower index) ----
    for (int r = 0; r < KRET; ++r) {
        unsigned long long best = ~0ull;
#pragma unroll
        for (int it = 0; it < 16; ++it) {
            unsigned long long p =
                ((unsigned long long)__float_as_uint(score[it]) << 32) |
                (unsigned int)(it * 256 + tid);
            best = best < p ? best : p;
        }
        for (int off = 32; off > 0; off >>= 1) {
            unsigned long long o = __shfl_down(best, off, 64);
            best = best < o ? best : o;
        }
        if ((tid & 63) == 0) s_red[tid >> 6] = best;
        __syncthreads();
        if (tid == 0) {
            unsigned long long w = s_red[0];
            w = w < s_red[1] ? w : s_red[1];
            w = w < s_red[2] ? w : s_red[2];
            w = w < s_red[3] ? w : s_red[3];
            s_win = w;
        }
        __syncthreads();
        unsigned long long w = s_win;
        int cj = (int)(w & 0xffffffffu);
        if (tid == (cj & 255)) score[cj >> 8] = 1e30f;  // remove chosen from candidates
        if (tid == 0) {
            s_negidx[r] = cj;
            s_negd[r] = __uint_as_float((unsigned int)(w >> 32));
        }
        __syncthreads();
    }

    // sort the 7 negatives by index ascending (matches jnp.sort(neg_idx))
    if (tid == 0) {
        for (int a = 1; a < KRET; ++a) {
            int ix = s_negidx[a]; float dv = s_negd[a];
            int b = a - 1;
            while (b >= 0 && s_negidx[b] > ix) {
                s_negidx[b + 1] = s_negidx[b];
                s_negd[b + 1] = s_negd[b];
                --b;
            }
            s_negidx[b + 1] = ix; s_negd[b + 1] = dv;
        }
    }
    __syncthreads();

    // ---- Phase 3: real Euclidean distances in `emb` for 7 pos + 7 neg pairs ----
    {
        int wave = tid >> 6, lane = tid & 63;
        int gb = i & ~(SPC - 1);
        for (int p = wave; p < 2 * KRET; p += 4) {
            int t;
            if (p < KRET) {
                int k = p;
                int m = k + (k >= (i & (SPC - 1)) ? 1 : 0);
                t = gb + m;
            } else {
                t = s_negidx[p - KRET];
            }
            float d0 = emb[(size_t)t * D + lane]      - s_anchor[lane];
            float d1 = emb[(size_t)t * D + 64 + lane] - s_anchor[64 + lane];
            float s = d0 * d0 + d1 * d1;
            for (int off = 32; off > 0; off >>= 1) s += __shfl_down(s, off, 64);
            if (lane == 0) s_dreal[p] = sqrtf(s + 1e-8f);
        }
    }
    __syncthreads();

    // ---- Epilogue: validity + loss accumulation ----
    if (tid == 0) {
        float ls = 0.f, cnt = 0.f;
        for (int k = 0; k < KRET; ++k) {
            int m = k + (k >= (i & (SPC - 1)) ? 1 : 0);
            float dpos = s_posd[m];        // cross-distance, pos pair k (index-ascending)
            float dneg = s_negd[k];        // cross-distance, neg pair k (index-ascending)
            if (dpos < dneg + MARGIN) {    // has_pos is always true (exactly 7 positives)
                float d_ap = s_dreal[k];
                float d_an = s_dreal[KRET + k];
                float pos_loss = d_ap + MARGIN;              // relu(d_ap+m) = d_ap+m
                float neg_loss = fmaxf(MARGIN - d_an, 0.f);
                ls += pos_loss + neg_loss;
                cnt += 1.f;                                  // active == 1 always
            }
        }
        if (ls != 0.f) atomicAdd(&ws_acc[0], ls);
        if (cnt != 0.f) atomicAdd(&ws_acc[1], cnt);
    }
}

__global__ void finalize_kernel(const float* __restrict__ ws_acc, float* __restrict__ out) {
    float ls = ws_acc[0], cnt = ws_acc[1];
    out[0] = cnt > 0.f ? ls / cnt : ls;
}

extern "C" void kernel_launch(void* const* d_in, const int* in_sizes, int n_in,
                              void* d_out, int out_size, void* d_ws, size_t ws_size,
                              hipStream_t stream) {
    const float* emb     = (const float*)d_in[0];
    const int*   labels  = (const int*)d_in[1];
    const float* emb1    = (const float*)d_in[2];
    const int*   labels1 = (const int*)d_in[3];
    float* ws   = (float*)d_ws;
    float* diag = ws + 2;

    hipMemsetAsync(d_ws, 0, 2 * sizeof(float), stream);
    diag_kernel<<<NROWS / 4, 256, 0, stream>>>(emb, emb1, diag);
    main_kernel<<<NROWS, 256, 0, stream>>>(emb, emb1, labels, labels1, diag, ws);
    finalize_kernel<<<1, 1, 0, stream>>>(ws, (float*)d_out);
}

// Round 2
// 205.838 us; speedup vs baseline: 4.5126x; 4.5126x over previous
//
#include <hip/hip_runtime.h>
#include <math.h>

#define NROWS 4096
#define D 128
#define SPC 8
#define KRET 7
#define MARGIN 0.2f

typedef unsigned long long u64;

// New-path ws layout (floats):
//   [0] loss_sum accum, [1] count accum
//   [4096 .. 8191]  diag
//   [8192 .. 8192 + 4096*4096) distance matrix M
// Fallback-path ws layout: [0],[1] accum, [2..2+NROWS) diag.

__global__ __launch_bounds__(256) void diag_kernel(const float* __restrict__ emb,
                                                   const float* __restrict__ emb1,
                                                   float* __restrict__ diag) {
    int wave = threadIdx.x >> 6;
    int lane = threadIdx.x & 63;
    int row = blockIdx.x * 4 + wave;
    const float* a = emb + (size_t)row * D;
    const float* b = emb1 + (size_t)row * D;
    float s = a[lane] * b[lane] + a[lane + 64] * b[lane + 64];
    for (int off = 32; off > 0; off >>= 1) s += __shfl_down(s, off, 64);
    if (lane == 0) diag[row] = s;
}

// ---------------- Distance GEMM: M[i][j] = sqrt(max(diag_i + diag_j - 2*dot, 1e-4)) ----------------
#define LDP 132  // padded LDS row stride (floats); 132*4=528 keeps float4 alignment

__global__ __launch_bounds__(256) void dist_kernel(const float* __restrict__ emb,
                                                   const float* __restrict__ emb1,
                                                   const float* __restrict__ diag,
                                                   float* __restrict__ M) {
    __shared__ float sA[D * LDP];   // sA[k*LDP + row] = emb[i0+row][k]
    __shared__ float sB[D * LDP];   // sB[k*LDP + col] = emb1[j0+col][k]
    __shared__ float sdA[128];
    __shared__ float sdB[128];

    const int t = threadIdx.x;
    const int i0 = blockIdx.y * 128, j0 = blockIdx.x * 128;

    {   // transposed staging: lanes read consecutive k of one row (coalesced 256B)
        const int half = t >> 7;      // 0/1
        const int k = t & 127;
        const float* pa = emb  + (size_t)(i0 + half) * D + k;
        const float* pb = emb1 + (size_t)(j0 + half) * D + k;
#pragma unroll 4
        for (int rr = 0; rr < 64; ++rr) {
            int row = rr * 2 + half;
            sA[k * LDP + row] = pa[(size_t)rr * 2 * D];
            sB[k * LDP + row] = pb[(size_t)rr * 2 * D];
        }
        if (t < 128) sdA[t] = diag[i0 + t];
        else         sdB[t - 128] = diag[j0 + t - 128];
    }
    __syncthreads();

    const int tx = t & 15, ty = t >> 4;
    const int r0 = 4 * ty, c0 = 4 * tx;
    float acc[8][8];
#pragma unroll
    for (int r = 0; r < 8; ++r)
#pragma unroll
        for (int c = 0; c < 8; ++c) acc[r][c] = 0.f;

#pragma unroll 4
    for (int k = 0; k < D; ++k) {
        const float* a = sA + k * LDP;
        const float* b = sB + k * LDP;
        float4 a0 = *(const float4*)(a + r0);
        float4 a1 = *(const float4*)(a + r0 + 64);
        float4 b0 = *(const float4*)(b + c0);
        float4 b1 = *(const float4*)(b + c0 + 64);
        float av[8] = {a0.x, a0.y, a0.z, a0.w, a1.x, a1.y, a1.z, a1.w};
        float bv[8] = {b0.x, b0.y, b0.z, b0.w, b1.x, b1.y, b1.z, b1.w};
#pragma unroll
        for (int r = 0; r < 8; ++r)
#pragma unroll
            for (int c = 0; c < 8; ++c)
                acc[r][c] = fmaf(av[r], bv[c], acc[r][c]);
    }

#pragma unroll
    for (int r = 0; r < 8; ++r) {
        int row = (r < 4) ? (r0 + r) : (64 + r0 + r - 4);
        float di = sdA[row];
        float4 o0, o1;
        o0.x = sqrtf(fmaxf(di + sdB[c0 + 0]      - 2.f * acc[r][0], 1e-4f));
        o0.y = sqrtf(fmaxf(di + sdB[c0 + 1]      - 2.f * acc[r][1], 1e-4f));
        o0.z = sqrtf(fmaxf(di + sdB[c0 + 2]      - 2.f * acc[r][2], 1e-4f));
        o0.w = sqrtf(fmaxf(di + sdB[c0 + 3]      - 2.f * acc[r][3], 1e-4f));
        o1.x = sqrtf(fmaxf(di + sdB[64 + c0 + 0] - 2.f * acc[r][4], 1e-4f));
        o1.y = sqrtf(fmaxf(di + sdB[64 + c0 + 1] - 2.f * acc[r][5], 1e-4f));
        o1.z = sqrtf(fmaxf(di + sdB[64 + c0 + 2] - 2.f * acc[r][6], 1e-4f));
        o1.w = sqrtf(fmaxf(di + sdB[64 + c0 + 3] - 2.f * acc[r][7], 1e-4f));
        float* dst = M + (size_t)(i0 + row) * NROWS + j0;
        *(float4*)(dst + c0) = o0;
        *(float4*)(dst + c0 + 64) = o1;
    }
}

// ---------------- Selection + real distances + loss per anchor row ----------------
__global__ __launch_bounds__(256) void select_kernel(const float* __restrict__ emb,
                                                     const float* __restrict__ M,
                                                     const int* __restrict__ labels,
                                                     const int* __restrict__ labels1,
                                                     float* __restrict__ ws_acc) {
    const int i = blockIdx.x;
    const int t = threadIdx.x;

    __shared__ float s_anchor[D];
    __shared__ float s_posd[SPC];
    __shared__ u64 s_red[2][4];
    __shared__ int s_negidx[KRET];
    __shared__ float s_negd[KRET];
    __shared__ float s_dreal[2 * KRET];

    if (t < D) s_anchor[t] = emb[(size_t)i * D + t];
    const int li = labels1[i];

    // coalesced row read: 4 float4 + 4 int4 per thread, scores stay in registers
    u64 sc[16];
    const float4* Mrow = (const float4*)(M + (size_t)i * NROWS);
    const int4* lab4 = (const int4*)labels;
#pragma unroll
    for (int it = 0; it < 4; ++it) {
        int idx4 = it * 256 + t;
        float4 d = Mrow[idx4];
        int4 L = lab4[idx4];
        float dv[4] = {d.x, d.y, d.z, d.w};
        int lv[4] = {L.x, L.y, L.z, L.w};
        int jb = idx4 * 4;
#pragma unroll
        for (int c = 0; c < 4; ++c) {
            int j = jb + c;
            bool pos = (lv[c] == li) && (j != i);
            if (pos) s_posd[j & (SPC - 1)] = dv[c];
            float score = dv[c] + (pos ? 1e6f : 0.f);
            sc[it * 4 + c] = ((u64)__float_as_uint(score) << 32) | (unsigned)j;
        }
    }
    __syncthreads();   // s_posd, s_anchor ready

    // 7 rounds of block argmin (packed score|index, tie-break lower index)
    for (int r = 0; r < KRET; ++r) {
        u64 best = ~0ull;
#pragma unroll
        for (int q = 0; q < 16; ++q) best = best < sc[q] ? best : sc[q];
        for (int off = 32; off > 0; off >>= 1) {
            u64 o = __shfl_down(best, off, 64);
            best = best < o ? best : o;
        }
        if ((t & 63) == 0) s_red[r & 1][t >> 6] = best;
        __syncthreads();
        u64 w = s_red[r & 1][0];
        w = w < s_red[r & 1][1] ? w : s_red[r & 1][1];
        w = w < s_red[r & 1][2] ? w : s_red[r & 1][2];
        w = w < s_red[r & 1][3] ? w : s_red[r & 1][3];
        // invalidate the winner (u64 equality is unique via index bits; no runtime indexing)
#pragma unroll
        for (int q = 0; q < 16; ++q) sc[q] = (sc[q] == w) ? ~0ull : sc[q];
        if (t == 0) {
            s_negidx[r] = (int)(w & 0xffffffffu);
            s_negd[r] = __uint_as_float((unsigned)(w >> 32));
        }
    }
    __syncthreads();

    // sort negatives by index ascending (matches jnp.sort(neg_idx))
    if (t == 0) {
        for (int a = 1; a < KRET; ++a) {
            int ix = s_negidx[a]; float dvv = s_negd[a];
            int b = a - 1;
            while (b >= 0 && s_negidx[b] > ix) {
                s_negidx[b + 1] = s_negidx[b];
                s_negd[b + 1] = s_negd[b];
                --b;
            }
            s_negidx[b + 1] = ix; s_negd[b + 1] = dvv;
        }
    }
    __syncthreads();

    // real Euclidean distances in emb for 7 pos + 7 neg pairs
    {
        int wave = t >> 6, lane = t & 63;
        int gb = i & ~(SPC - 1);
        for (int p = wave; p < 2 * KRET; p += 4) {
            int tgt;
            if (p < KRET) {
                int k = p;
                int m = k + (k >= (i & (SPC - 1)) ? 1 : 0);
                tgt = gb + m;
            } else {
                tgt = s_negidx[p - KRET];
            }
            float d0 = emb[(size_t)tgt * D + lane]      - s_anchor[lane];
            float d1 = emb[(size_t)tgt * D + 64 + lane] - s_anchor[64 + lane];
            float s = d0 * d0 + d1 * d1;
            for (int off = 32; off > 0; off >>= 1) s += __shfl_down(s, off, 64);
            if (lane == 0) s_dreal[p] = sqrtf(s + 1e-8f);
        }
    }
    __syncthreads();

    if (t == 0) {
        float ls = 0.f, cnt = 0.f;
        for (int k = 0; k < KRET; ++k) {
            int m = k + (k >= (i & (SPC - 1)) ? 1 : 0);
            float dpos = s_posd[m];
            float dneg = s_negd[k];
            if (dpos < dneg + MARGIN) {
                float d_ap = s_dreal[k];
                float d_an = s_dreal[KRET + k];
                ls += (d_ap + MARGIN) + fmaxf(MARGIN - d_an, 0.f);
                cnt += 1.f;
            }
        }
        if (ls != 0.f) atomicAdd(&ws_acc[0], ls);
        if (cnt != 0.f) atomicAdd(&ws_acc[1], cnt);
    }
}

// ---------------- Fallback (round-1 fused kernel) ----------------
__global__ __launch_bounds__(256) void main_kernel(const float* __restrict__ emb,
                                                   const float* __restrict__ emb1,
                                                   const int* __restrict__ labels,
                                                   const int* __restrict__ labels1,
                                                   const float* __restrict__ diag,
                                                   float* __restrict__ ws_acc) {
    const int i = blockIdx.x;
    const int tid = threadIdx.x;

    __shared__ float s_anchor[D];
    __shared__ float s_posd[SPC];
    __shared__ unsigned long long s_red[4];
    __shared__ unsigned long long s_win;
    __shared__ int s_negidx[KRET];
    __shared__ float s_negd[KRET];
    __shared__ float s_dreal[2 * KRET];

    if (tid < D) s_anchor[tid] = emb[(size_t)i * D + tid];
    __syncthreads();

    const float diag_i = diag[i];
    const int li = labels1[i];

    float score[16];
#pragma unroll
    for (int it = 0; it < 16; ++it) {
        int j = it * 256 + tid;
        const float4* r = (const float4*)(emb1 + (size_t)j * D);
        float acc = 0.f;
#pragma unroll
        for (int q = 0; q < D / 4; ++q) {
            float4 v = r[q];
            acc = fmaf(v.x, s_anchor[4 * q + 0], acc);
            acc = fmaf(v.y, s_anchor[4 * q + 1], acc);
            acc = fmaf(v.z, s_anchor[4 * q + 2], acc);
            acc = fmaf(v.w, s_anchor[4 * q + 3], acc);
        }
        float d2 = diag_i + diag[j] - 2.f * acc;
        float dist = sqrtf(fmaxf(d2, 1e-4f));
        bool is_pos = (labels[j] == li) && (j != i);
        if (is_pos) s_posd[j & (SPC - 1)] = dist;
        score[it] = dist + (is_pos ? 1e6f : 0.f);
    }
    __syncthreads();

    for (int r = 0; r < KRET; ++r) {
        unsigned long long best = ~0ull;
#pragma unroll
        for (int it = 0; it < 16; ++it) {
            unsigned long long p =
                ((unsigned long long)__float_as_uint(score[it]) << 32) |
                (unsigned int)(it * 256 + tid);
            best = best < p ? best : p;
        }
        for (int off = 32; off > 0; off >>= 1) {
            unsigned long long o = __shfl_down(best, off, 64);
            best = best < o ? best : o;
        }
        if ((tid & 63) == 0) s_red[tid >> 6] = best;
        __syncthreads();
        if (tid == 0) {
            unsigned long long w = s_red[0];
            w = w < s_red[1] ? w : s_red[1];
            w = w < s_red[2] ? w : s_red[2];
            w = w < s_red[3] ? w : s_red[3];
            s_win = w;
        }
        __syncthreads();
        unsigned long long w = s_win;
        int cj = (int)(w & 0xffffffffu);
        if (tid == (cj & 255)) score[cj >> 8] = 1e30f;
        if (tid == 0) {
            s_negidx[r] = cj;
            s_negd[r] = __uint_as_float((unsigned int)(w >> 32));
        }
        __syncthreads();
    }

    if (tid == 0) {
        for (int a = 1; a < KRET; ++a) {
            int ix = s_negidx[a]; float dv = s_negd[a];
            int b = a - 1;
            while (b >= 0 && s_negidx[b] > ix) {
                s_negidx[b + 1] = s_negidx[b];
                s_negd[b + 1] = s_negd[b];
                --b;
            }
            s_negidx[b + 1] = ix; s_negd[b + 1] = dv;
        }
    }
    __syncthreads();

    {
        int wave = tid >> 6, lane = tid & 63;
        int gb = i & ~(SPC - 1);
        for (int p = wave; p < 2 * KRET; p += 4) {
            int tgt;
            if (p < KRET) {
                int k = p;
                int m = k + (k >= (i & (SPC - 1)) ? 1 : 0);
                tgt = gb + m;
            } else {
                tgt = s_negidx[p - KRET];
            }
            float d0 = emb[(size_t)tgt * D + lane]      - s_anchor[lane];
            float d1 = emb[(size_t)tgt * D + 64 + lane] - s_anchor[64 + lane];
            float s = d0 * d0 + d1 * d1;
            for (int off = 32; off > 0; off >>= 1) s += __shfl_down(s, off, 64);
            if (lane == 0) s_dreal[p] = sqrtf(s + 1e-8f);
        }
    }
    __syncthreads();

    if (tid == 0) {
        float ls = 0.f, cnt = 0.f;
        for (int k = 0; k < KRET; ++k) {
            int m = k + (k >= (i & (SPC - 1)) ? 1 : 0);
            float dpos = s_posd[m];
            float dneg = s_negd[k];
            if (dpos < dneg + MARGIN) {
                float d_ap = s_dreal[k];
                float d_an = s_dreal[KRET + k];
                ls += (d_ap + MARGIN) + fmaxf(MARGIN - d_an, 0.f);
                cnt += 1.f;
            }
        }
        if (ls != 0.f) atomicAdd(&ws_acc[0], ls);
        if (cnt != 0.f) atomicAdd(&ws_acc[1], cnt);
    }
}

__global__ void finalize_kernel(const float* __restrict__ ws_acc, float* __restrict__ out) {
    float ls = ws_acc[0], cnt = ws_acc[1];
    out[0] = cnt > 0.f ? ls / cnt : ls;
}

extern "C" void kernel_launch(void* const* d_in, const int* in_sizes, int n_in,
                              void* d_out, int out_size, void* d_ws, size_t ws_size,
                              hipStream_t stream) {
    const float* emb     = (const float*)d_in[0];
    const int*   labels  = (const int*)d_in[1];
    const float* emb1    = (const float*)d_in[2];
    const int*   labels1 = (const int*)d_in[3];
    float* ws = (float*)d_ws;

    hipMemsetAsync(d_ws, 0, 2 * sizeof(float), stream);

    size_t need = ((size_t)8192 + (size_t)NROWS * NROWS) * sizeof(float);
    if (ws_size >= need) {
        float* diag = ws + 4096;
        float* M    = ws + 8192;
        diag_kernel<<<NROWS / 4, 256, 0, stream>>>(emb, emb1, diag);
        dim3 grid(NROWS / 128, NROWS / 128);
        dist_kernel<<<grid, 256, 0, stream>>>(emb, emb1, diag, M);
        select_kernel<<<NROWS, 256, 0, stream>>>(emb, M, labels, labels1, ws);
        finalize_kernel<<<1, 1, 0, stream>>>(ws, (float*)d_out);
    } else {
        float* diag = ws + 2;
        diag_kernel<<<NROWS / 4, 256, 0, stream>>>(emb, emb1, diag);
        main_kernel<<<NROWS, 256, 0, stream>>>(emb, emb1, labels, labels1, diag, ws);
        finalize_kernel<<<1, 1, 0, stream>>>(ws, (float*)d_out);
    }
}